// Round 7
// baseline (227.571 us; speedup 1.0000x reference)
//
#include <hip/hip_runtime.h>
#include <math.h>

#define N1 2000
#define N2 2000
#define NT 4000
#define D  63
#define E  64
#define H  8
#define KNN 5
#define NPAD 4032   // n padded: 63 blocks of 64
#define MPAD 4096   // m padded: 16 blocks of 256

typedef short bf16x8 __attribute__((ext_vector_type(8)));
typedef float f32x4  __attribute__((ext_vector_type(4)));

__device__ __forceinline__ unsigned short f2bf(float x) {
    unsigned u = __float_as_uint(x);
    u = (u + 0x7fffu + ((u >> 16) & 1u)) >> 16;   // RN-even
    return (unsigned short)u;
}

// ---------------------------------------------------------------- k_d2
// 64x64 tile, 4x4 register blocking, K padded 63->64, float4 LDS (stride 68).
// sq (row self-dot) fused: computed from staged LDS tiles by waves 0/1.
__global__ __launch_bounds__(256) void k_d2(const float* __restrict__ X,
                                            float* __restrict__ d2) {
    __shared__ float Xi[64][68];
    __shared__ float Xj[64][68];
    __shared__ float sqi[64], sqj[64];
    int i0 = blockIdx.y * 64, j0 = blockIdx.x * 64;
    int tid = threadIdx.x;
    for (int t = tid; t < 64 * 64; t += 256) {
        int r = t >> 6, c = t & 63;
        int gi = min(i0 + r, N1 - 1);
        int gj = min(j0 + r, N1 - 1);
        Xi[r][c] = (c < D) ? X[gi * D + c] : 0.f;
        Xj[r][c] = (c < D) ? X[gj * D + c] : 0.f;
    }
    __syncthreads();
    {
        int lane = tid & 63, wave = tid >> 6;
        if (wave < 2) {
            const float(*Xr)[68] = (wave == 0) ? Xi : Xj;
            float s = 0.f;
            #pragma unroll
            for (int k = 0; k < 16; ++k) {
                float4 v = *(const float4*)&Xr[lane][4 * k];
                s += v.x * v.x + v.y * v.y + v.z * v.z + v.w * v.w;
            }
            if (wave == 0) sqi[lane] = s; else sqj[lane] = s;
        }
    }
    __syncthreads();
    int tx = tid & 15, ty = tid >> 4;
    float acc[4][4];
    #pragma unroll
    for (int a = 0; a < 4; ++a)
        #pragma unroll
        for (int b = 0; b < 4; ++b) acc[a][b] = 0.f;

    #pragma unroll 4
    for (int kk = 0; kk < 16; ++kk) {
        float4 av[4], bv[4];
        #pragma unroll
        for (int ii = 0; ii < 4; ++ii) av[ii] = *(const float4*)&Xi[ty + 16 * ii][4 * kk];
        #pragma unroll
        for (int jj = 0; jj < 4; ++jj) bv[jj] = *(const float4*)&Xj[tx + 16 * jj][4 * kk];
        #pragma unroll
        for (int ii = 0; ii < 4; ++ii)
            #pragma unroll
            for (int jj = 0; jj < 4; ++jj)
                acc[ii][jj] += av[ii].x * bv[jj].x + av[ii].y * bv[jj].y +
                               av[ii].z * bv[jj].z + av[ii].w * bv[jj].w;
    }

    #pragma unroll
    for (int ii = 0; ii < 4; ++ii) {
        int i = i0 + ty + 16 * ii;
        #pragma unroll
        for (int jj = 0; jj < 4; ++jj) {
            int j = j0 + tx + 16 * jj;
            if (i < N1 && j < N1) {
                float v = sqi[ty + 16 * ii] + sqj[tx + 16 * jj] - 2.f * acc[ii][jj];
                if (i == j) v = __builtin_inff();
                d2[i * N1 + j] = v;
            }
        }
    }
}

// ---------------------------------------------------------------- k_top5
__device__ __forceinline__ bool dless(float d1, int i1, float d2v, int i2) {
    return d1 < d2v || (d1 == d2v && i1 < i2);   // stable top_k tie-break
}

__device__ __forceinline__ void ins5(float bd[KNN], int bi[KNN], float d, int j) {
    if (dless(d, j, bd[KNN - 1], bi[KNN - 1])) {
        bd[KNN - 1] = d; bi[KNN - 1] = j;
        #pragma unroll
        for (int s = KNN - 1; s > 0; --s) {
            if (dless(bd[s], bi[s], bd[s - 1], bi[s - 1])) {
                float td = bd[s]; bd[s] = bd[s - 1]; bd[s - 1] = td;
                int ti = bi[s]; bi[s] = bi[s - 1]; bi[s - 1] = ti;
            }
        }
    }
}

// One row per block. Lane-local top5 -> per-wave butterfly min-extract x5 ->
// 20-candidate final butterfly merge in wave 0.
__global__ __launch_bounds__(256) void k_top5(const float* __restrict__ d2,
                                              const float* __restrict__ lmY,
                                              float* __restrict__ ypred,
                                              int* __restrict__ idx) {
    __shared__ float sd[4 * KNN];
    __shared__ int   si[4 * KNN];
    int i = blockIdx.x;
    int tid = threadIdx.x;
    const float* row = d2 + i * N1;

    float bd[KNN]; int bi[KNN];
    #pragma unroll
    for (int s = 0; s < KNN; ++s) { bd[s] = __builtin_inff(); bi[s] = 0x7fffffff; }
    #pragma unroll
    for (int k = 0; k < 8; ++k) {
        int j = tid + k * 256;
        if (j < N1) ins5(bd, bi, row[j], j);
    }

    int lane = tid & 63, wave = tid >> 6;
    float wd[KNN]; int wi[KNN];
    #pragma unroll
    for (int s = 0; s < KNN; ++s) {
        float d = bd[0]; int ix = bi[0];
        #pragma unroll
        for (int m = 1; m < 64; m <<= 1) {
            float od = __shfl_xor(d, m, 64);
            int   oi = __shfl_xor(ix, m, 64);
            if (dless(od, oi, d, ix)) { d = od; ix = oi; }
        }
        wd[s] = d; wi[s] = ix;
        if (d == bd[0] && ix == bi[0]) {
            #pragma unroll
            for (int q = 0; q < KNN - 1; ++q) { bd[q] = bd[q + 1]; bi[q] = bi[q + 1]; }
            bd[KNN - 1] = __builtin_inff(); bi[KNN - 1] = 0x7fffffff;
        }
    }
    if (lane == 0) {
        #pragma unroll
        for (int s = 0; s < KNN; ++s) { sd[wave * KNN + s] = wd[s]; si[wave * KNN + s] = wi[s]; }
    }
    __syncthreads();
    if (wave == 0) {
        float d = (lane < 4 * KNN) ? sd[lane] : __builtin_inff();
        int  ix = (lane < 4 * KNN) ? si[lane] : 0x7fffffff;
        float rd[KNN]; int ri[KNN];
        #pragma unroll
        for (int s = 0; s < KNN; ++s) {
            float md = d; int mi = ix;
            #pragma unroll
            for (int m = 1; m < 64; m <<= 1) {
                float od = __shfl_xor(md, m, 64);
                int   oi = __shfl_xor(mi, m, 64);
                if (dless(od, oi, md, mi)) { md = od; mi = oi; }
            }
            rd[s] = md; ri[s] = mi;
            if (md == d && mi == ix) { d = __builtin_inff(); ix = 0x7fffffff; }
        }
        if (lane == 0) {
            float y0 = 0.f, y1 = 0.f;
            #pragma unroll
            for (int s = 0; s < KNN; ++s) {
                int j = ri[s];
                y0 += lmY[j * 2];
                y1 += lmY[j * 2 + 1];
                idx[i * KNN + s] = j;
            }
            ypred[i * 2]     = y0 * 0.2f;
            ypred[i * 2 + 1] = y1 * 0.2f;
        }
    }
}

// ---------------------------------------------------------------- k_prep
// 4 nodes per block (1 per wave); W_emb staged in LDS once per block.
// AL fold: +1/||a||. Bbuf = bf16(e). sB = 1/||b||.
__global__ __launch_bounds__(256) void k_prep(const float* __restrict__ lmX,
                                              const float* __restrict__ tgX,
                                              const float* __restrict__ lmD,
                                              const float* __restrict__ tgD,
                                              const float* __restrict__ W,
                                              const float* __restrict__ bias,
                                              const float* __restrict__ w1,
                                              const float* __restrict__ w2,
                                              unsigned short* __restrict__ AL,
                                              unsigned short* __restrict__ Bbuf,
                                              float* __restrict__ sB) {
    __shared__ float f[4][E];
    __shared__ float Wl[E][68];
    int tid = threadIdx.x, lane = tid & 63, wave = tid >> 6;
    int n = blockIdx.x * 4 + wave;
    #pragma unroll
    for (int k = 0; k < 4; ++k) {
        int g = k * 256 + tid;
        float4 v = ((const float4*)W)[g];
        int r = g >> 4, c = (g & 15) * 4;
        *(float4*)&Wl[r][c] = v;
    }
    int t = lane;
    if (t < D)  f[wave][t] = (n < N1) ? lmX[n * D + t] : tgX[(n - N1) * D + t];
    if (t == D) f[wave][t] = (n < N1) ? lmD[n] : tgD[n - N1];
    __syncthreads();
    float s0 = 0.f, s1 = 0.f, s2 = 0.f, s3 = 0.f;
    #pragma unroll
    for (int k = 0; k < 16; ++k) {
        float4 wv = *(const float4*)&Wl[t][4 * k];
        float4 fv = *(const float4*)&f[wave][4 * k];
        s0 += fv.x * wv.x; s1 += fv.y * wv.y; s2 += fv.z * wv.z; s3 += fv.w * wv.w;
    }
    const float en = bias[t] + (s0 + s1) + (s2 + s3);
    Bbuf[n * E + t] = f2bf(en);

    int kc = t >> 5, kq = (t >> 3) & 3, j = t & 7;
    int alane = kq * 16 + (n & 15);
    int nb = n >> 4;
    #pragma unroll
    for (int h = 0; h < H; ++h) {
        float a = en * w1[t * H + h];
        float b = en * w2[t * H + h];
        float na2 = a * a, nb2 = b * b;
        #pragma unroll
        for (int m = 32; m >= 1; m >>= 1) {
            na2 += __shfl_xor(na2, m, 64);
            nb2 += __shfl_xor(nb2, m, 64);
        }
        float val = a * w2[t * H + h] * rsqrtf(na2);   // folds 1/||a||
        AL[(((nb * 8 + h) << 1) + kc) * 512 + alane * 8 + j] = f2bf(val);
        if (t == h) sB[n * H + h] = rsqrtf(nb2);
    }
}

// ---------------------------------------------------------------- k_adjm
// Block: 4 waves, tile 64(n) x 256(m). B tile in LDS (pad 66: 2-way = free),
// A frags in registers. B-fragments rotated one mt ahead (LDS latency hidden
// behind MFMA/epilogue). adjT pattern fill interleaved per-mt per-wave
// (spreads the 64MB store stream); KNN scatter after one barrier.
// Polynomial sigmoid epilogue (sim in [-1,1], |err|<=5e-5).
__global__ __launch_bounds__(256, 4) void k_adjm(const unsigned short* __restrict__ AL,
                                                 const unsigned short* __restrict__ Bbuf,
                                                 const float* __restrict__ sB,
                                                 const int* __restrict__ idx,
                                                 float* __restrict__ adj,
                                                 float* __restrict__ adjT) {
    __shared__ unsigned short Bt[256][66];   // 33,792 B
    int tid = threadIdx.x;
    int m0 = blockIdx.x * 256, n0 = blockIdx.y * 64;

    #pragma unroll
    for (int it = 0; it < 8; ++it) {
        int g = it * 256 + tid;
        int row = g >> 3, c = g & 7;
        *(bf16x8*)&Bt[row][c * 8] = *(const bf16x8*)&Bbuf[(m0 + row) * E + c * 8];
    }

    int wave = tid >> 6, lane = tid & 63;
    int l15 = lane & 15, kq = lane >> 4;
    int nb = blockIdx.y * 4 + wave;

    bf16x8 afr[H][2];
    #pragma unroll
    for (int h = 0; h < H; ++h)
        #pragma unroll
        for (int kc = 0; kc < 2; ++kc)
            afr[h][kc] = *(const bf16x8*)&AL[(((nb * 8 + h) << 1) + kc) * 512 + lane * 8];

    __syncthreads();

    int nebase = n0 + wave * 16 + kq * 4;
    // adjT fill coords for this lane: one float4 per mt
    int trow = n0 + wave * 16 + l15;
    int tcol0 = m0 + (lane >> 4) * 4;
    bool trowlm = trow < N1;
    bool trowok = trow < NT;

    bf16x8 b0 = *(const bf16x8*)&Bt[l15][kq * 8];
    bf16x8 b1 = *(const bf16x8*)&Bt[l15][32 + kq * 8];

    for (int mt = 0; mt < 16; ++mt) {
        int mrow = mt * 16 + l15;
        int mcol = m0 + mrow;

        float sbv[H];
        *(f32x4*)&sbv[0] = *(const f32x4*)&sB[mcol * H + 0];
        *(f32x4*)&sbv[4] = *(const f32x4*)&sB[mcol * H + 4];

        bf16x8 nb0, nb1;
        if (mt < 15) {
            nb0 = *(const bf16x8*)&Bt[mrow + 16][kq * 8];
            nb1 = *(const bf16x8*)&Bt[mrow + 16][32 + kq * 8];
        }

        f32x4 acc[H];
        #pragma unroll
        for (int h = 0; h < H; ++h) {
            acc[h] = (f32x4){0.f, 0.f, 0.f, 0.f};
            acc[h] = __builtin_amdgcn_mfma_f32_16x16x32_bf16(afr[h][0], b0, acc[h], 0, 0, 0);
            acc[h] = __builtin_amdgcn_mfma_f32_16x16x32_bf16(afr[h][1], b1, acc[h], 0, 0, 0);
        }

        // adjT pattern fill chunk for this mt (cols m0+mt*16 .. +15)
        {
            int col = tcol0 + mt * 16;
            if (trowok && col < NT) {
                float v = (trowlm != (col < N1)) ? 1.f : 0.f;
                float4 o = {v, v, v, v};
                *(float4*)&adjT[trow * NT + col] = o;
            }
        }

        bool mok = (mcol < NT);
        #pragma unroll
        for (int reg = 0; reg < 4; ++reg) {
            int ne = nebase + reg;
            float sum = 0.f;
            #pragma unroll
            for (int h = 0; h < H; ++h) {
                float x = acc[h][reg] * sbv[h];               // sim, in [-1,1]
                float u = x * x;
                float p = fmaf(u, 1.8919e-3f, -2.0833333e-2f);
                p = fmaf(u, p, 0.25f);
                sum = fmaf(x, p, sum);                        // += sigma(x)-0.5
            }
            if (mok && ne < NT) adj[ne * NT + mcol] = fmaf(sum, 0.125f, 0.5f);
        }

        b0 = nb0; b1 = nb1;
    }

    __syncthreads();                             // order scatter after fill
    // ---- KNN scatter: rows n0..n0+63 (lm only), cols within this tile ----
    for (int p = tid; p < 64 * KNN; p += 256) {
        int r = p / KNN, s = p - r * KNN;
        int row = n0 + r;
        if (row < N1) {
            int jx = idx[row * KNN + s];
            if (jx >= m0 && jx < m0 + 256) adjT[row * NT + jx] = 1.f;
        }
    }
}

// ---------------------------------------------------------------- launch
extern "C" void kernel_launch(void* const* d_in, const int* in_sizes, int n_in,
                              void* d_out, int out_size, void* d_ws, size_t ws_size,
                              hipStream_t stream) {
    const float* lmX  = (const float*)d_in[0];
    const float* lmY  = (const float*)d_in[1];
    const float* tgX  = (const float*)d_in[2];
    const float* lmD  = (const float*)d_in[4];
    const float* tgD  = (const float*)d_in[5];
    const float* Wemb = (const float*)d_in[6];
    const float* bemb = (const float*)d_in[7];
    const float* w1   = (const float*)d_in[8];
    const float* w2   = (const float*)d_in[9];

    float* out   = (float*)d_out;
    float* ypred = out;                          // [N1,2]
    float* adj   = out + 4000;                   // [NT,NT]
    float* adjT  = out + 4000 + 16000000;        // [NT,NT]

    // scratch in d_ws (~4.83 MB)
    char* ws = (char*)d_ws;
    unsigned short* AL   = (unsigned short*)ws;                  // 4,128,768 B
    unsigned short* Bbuf = (unsigned short*)(ws + 4128768);      //   524,288 B
    float*          sB   = (float*)(ws + 4128768 + 524288);      //   131,072 B
    int*            idx  = (int*)  (ws + 4784128);               //    40,000 B

    // d2 staged in adj region (consumed by k_top5 before k_adjm writes adj)
    float* d2 = adj;

    dim3 g2((N1 + 63) / 64, (N1 + 63) / 64);
    k_d2<<<g2, 256, 0, stream>>>(lmX, d2);
    k_top5<<<N1, 256, 0, stream>>>(d2, lmY, ypred, idx);
    k_prep<<<NT / 4, 256, 0, stream>>>(lmX, tgX, lmD, tgD, Wemb, bemb, w1, w2,
                                       AL, Bbuf, sB);
    dim3 ga(MPAD / 256, NPAD / 64);
    k_adjm<<<ga, 256, 0, stream>>>(AL, Bbuf, sB, idx, adj, adjT);
}